// Round 9
// baseline (325.410 us; speedup 1.0000x reference)
//
#include <hip/hip_runtime.h>

#define S_LEN  2048
#define BATCH  1024
#define NL     6
#define CH     16      // timesteps per chunk (x-prefetch granularity)

typedef float f32x2 __attribute__((ext_vector_type(2)));

__device__ __forceinline__ float fexp2(float x) { return __builtin_amdgcn_exp2f(x); }
__device__ __forceinline__ float frcp(float x)  { return __builtin_amdgcn_rcpf(x); }

// quad_perm DPP: 0xB1 = lane^1 (pair partner), 0x4E = lane^2 (unit^1)
template <int CTRL>
__device__ __forceinline__ float dppf(float v) {
    return __int_as_float(__builtin_amdgcn_update_dpp(
        0, __float_as_int(v), CTRL, 0xF, 0xF, true));
}
__device__ __forceinline__ float bpermf(int addr, float v) {
    return __int_as_float(__builtin_amdgcn_ds_bpermute(addr, __float_as_int(v)));
}
// lane^4 exchange (unit^2) via ds_swizzle BitMode: xor=4, and=0x1F -> 0x101F
__device__ __forceinline__ float swz4(float v) {
    return __int_as_float(__builtin_amdgcn_ds_swizzle(__float_as_int(v), 0x101F));
}
// packed fp32 fma: d.lo = a.lo*b.lo + c.lo ; d.hi = a.hi*b.hi + c.hi
__device__ __forceinline__ f32x2 pkfma(f32x2 a, f32x2 b, f32x2 c) {
    f32x2 d;
    asm("v_pk_fma_f32 %0, %1, %2, %3" : "=v"(d) : "v"(a), "v"(b), "v"(c));
    return d;
}

// ONE wave = ONE batch element; 1024 waves fill all 1024 SIMDs.
// lane = L*8 + u*2 + p: L 0..5 layers, L=6 head, L=7 feeders; u = unit,
// p = gate-pair (p=0 -> {i,f}, p=1 -> {g,o}).
//
// SKEW-3 pipeline: layer L at step n computes t = n - 3L. Consequences:
//  * E-block (hup half of the gate sums) for step n+1 runs at the TOP of
//    step n, from hup that landed >= 1 full step ago. Its ~10 instructions
//    sit between swz4(hn) [issued end of step n-1] and the F-chain's H2
//    consumer -> the on-chain LDS swizzle latency is fully covered.
//  * bpermute ring (hupM -> hupE -> E) has 2 steps of slack; swz4(hupM)
//    for the next E is staged mid-step under the activation latency.
// F-chain: own-h (register) hop first, swz-dependent H2 hop last.
// hn = fma(2*ssel, rT, -ssel) with 2*ssel precomputed off-chain.
// Cell state KGc-scaled; both parities compute valid cn/hn; head rides in
// the gHi chain of the L=6 lanes (reg_w as hup coefficients).
__global__ __launch_bounds__(64, 1) void lstm_wavepipe(
    const float* __restrict__ x, const float* __restrict__ w_ih,
    const float* __restrict__ w_hh, const float* __restrict__ b_ih,
    const float* __restrict__ b_hh, const float* __restrict__ reg_w,
    const float* __restrict__ reg_b, float* __restrict__ out) {
    const int lane = threadIdx.x;
    const int L    = lane >> 3;
    const int q    = lane & 7;
    const int u    = q >> 1;
    const bool pOdd = (lane & 1);
    const int b    = blockIdx.x;
    const bool isFeeder = (L == 7);
    const bool isOut    = (lane == 48);      // head lane u=0,p=0

    const float KGc = -2.885390082f;         // -2*log2(e)  (tanh scale)
    const float KIc = -1.442695041f;         // -log2(e)    (sigmoid scale)

    // ---- weight preload (R8 layout) ----
    // F1.x: gateLo h-terms {u,u^2}; F1.y: gateHi h-terms {u^1,u^3}
    // F2.x: gateHi h-terms {u,u^2}; F2.y: gateLo h-terms {u^1,u^3}
    // E1/E2 same with w_ih (hup); biases seed E1 via PB.
    f32x2 A1h[2], A2h[2], B1h[2], B2h[2], PB;
    if (L < NL) {
        const int gLoI = pOdd ? 2 : 0;       // i or g
        const int gHiI = pOdd ? 3 : 1;       // f or o
        const float klo = pOdd ? KGc : KIc;
        const float khi = KIc;
        const int rowLo = L * 16 + gLoI * 4 + u;
        const int rowHi = L * 16 + gHiI * 4 + u;
#pragma unroll
        for (int k = 0; k < 2; ++k) {        // k=0: {u,u^1}; k=1: {u^2,u^3}
            const int c0 = u ^ (2 * k);
            const int c1 = u ^ (2 * k + 1);
            f32x2 a1, a2, b1, b2;
            a1.x = w_hh[rowLo * 4 + c0] * klo; a1.y = w_hh[rowHi * 4 + c1] * khi;
            a2.x = w_hh[rowHi * 4 + c0] * khi; a2.y = w_hh[rowLo * 4 + c1] * klo;
            b1.x = w_ih[rowLo * 4 + c0] * klo; b1.y = w_ih[rowHi * 4 + c1] * khi;
            b2.x = w_ih[rowHi * 4 + c0] * khi; b2.y = w_ih[rowLo * 4 + c1] * klo;
            A1h[k] = a1; A2h[k] = a2; B1h[k] = b1; B2h[k] = b2;
        }
        PB.x = (b_ih[rowLo] + b_hh[rowLo]) * klo;
        PB.y = (b_ih[rowHi] + b_hh[rowHi]) * khi;
    } else if (L == 6) {                     // head: dot(reg_w, hup) in gHi
#pragma unroll
        for (int k = 0; k < 2; ++k) {
            f32x2 z; z.x = 0.0f; z.y = 0.0f;
            A1h[k] = z; A2h[k] = z;
            f32x2 b1; b1.x = 0.0f; b1.y = reg_w[u ^ (2 * k + 1)];
            f32x2 b2; b2.x = reg_w[u ^ (2 * k)]; b2.y = 0.0f;
            B1h[k] = b1; B2h[k] = b2;
        }
        PB.x = 0.0f; PB.y = reg_b[0];
    } else {                                 // feeders: all zero
#pragma unroll
        for (int k = 0; k < 2; ++k) {
            f32x2 z; z.x = 0.0f; z.y = 0.0f;
            A1h[k] = z; A2h[k] = z; B1h[k] = z; B2h[k] = z;
        }
        PB.x = 0.0f; PB.y = 0.0f;
    }
    // sA = fma(aLo, rA, bLo): p0 -> KGc*sigmoid(i), p1 -> tanh(g)
    const float aLo = pOdd ? 2.0f : KGc;
    const float bLo = pOdd ? -1.0f : 0.0f;
    f32x2 Z2; Z2.x = 0.0f; Z2.y = 0.0f;

    const int addrA = (((lane >= 8) ? (lane - 8) : (lane + 56)) << 2);

    float cp = 0.0f;                         // KGc-scaled cell state
    float Hx = 0.0f, H2x = 0.0f;             // h, h[u^2] (swz-staged)
    float bufP[CH], bufQ[CH], su[CH];
    const uint32_t xcol = (uint32_t)(b * 4 + u);
    uint32_t wi = xcol;
#pragma unroll
    for (int uu = 0; uu < CH; ++uu) { bufP[uu] = x[wi]; wi += 4096; }  // t=0..15

    // prologue (skew-3): feeders publish x[n+3] at step n, so seed with
    // x[0] (E for step 0), x[1] (E for step 1), x[2] (hupM -> E for step 2).
    const float pub0 = isFeeder ? bufP[0] : 0.0f;
    const float pub1 = isFeeder ? bufP[1] : 0.0f;
    const float pub2 = isFeeder ? bufP[2] : 0.0f;
    f32x2 E1c, E2c;
    {
        const float h0 = bpermf(addrA, pub0);
        f32x2 U0; U0.x = h0; U0.y = dppf<0x4E>(h0);
        const float u20 = swz4(h0);
        f32x2 U2; U2.x = u20; U2.y = dppf<0x4E>(u20);
        E1c = pkfma(B1h[1], U2, pkfma(B1h[0], U0, PB));
        E2c = pkfma(B2h[1], U2, pkfma(B2h[0], U0, Z2));
    }
    float hupE = bpermf(addrA, pub1);        // consumed by E-block at step 0
    float U2s  = swz4(hupE);                 // its u^2 companion
    float hupM = bpermf(addrA, pub2);        // becomes hupE at step 1

// one pipeline step; NXV_ = x value the feeders publish (consumed at n+3)
#define STEP(u_, NXV_, MASKF_) do {                                            \
    /* E-block for step n+1 (indep of this step's h; covers swz4(hn_prev)) */  \
    f32x2 Un, U2n;                                                             \
    Un.x = hupE;  Un.y = dppf<0x4E>(hupE);                                     \
    U2n.x = U2s;  U2n.y = dppf<0x4E>(U2s);                                     \
    f32x2 E1n = pkfma(B1h[0], Un, PB);                                         \
    f32x2 E2n = pkfma(B2h[0], Un, Z2);                                         \
    E1n = pkfma(B1h[1], U2n, E1n);                                             \
    E2n = pkfma(B2h[1], U2n, E2n);                                             \
    /* F-chain: own-h hop first, swz-dependent H2 hop last */                  \
    f32x2 Hh, H2h;                                                             \
    Hh.x = Hx;   Hh.y = dppf<0x4E>(Hx);                                        \
    H2h.x = H2x; H2h.y = dppf<0x4E>(H2x);                                      \
    f32x2 F1 = pkfma(A1h[0], Hh, E1c);                                         \
    f32x2 F2 = pkfma(A2h[0], Hh, E2c);                                         \
    F1 = pkfma(A1h[1], H2h, F1);                                               \
    F2 = pkfma(A2h[1], H2h, F2);                                               \
    const float gLo = F1.x + F2.y;                                             \
    const float gHi = F1.y + F2.x;                                             \
    /* stage swz of the in-flight hup (for next step's E-block) */             \
    const float U2sN = swz4(hupM);                                             \
    /* activations */                                                          \
    const float rA = frcp(1.0f + fexp2(gLo));                                  \
    const float rB = frcp(1.0f + fexp2(gHi));                                  \
    const float sA = fmaf(aLo, rA, bLo);     /* p0: KGc*si ; p1: tanh(g) */    \
    const float X  = dppf<0xB1>(sA);                                           \
    const float Y  = dppf<0xB1>(rB);                                           \
    const float fsel = pOdd ? Y : rB;        /* sigmoid(f) on both lanes */    \
    const float ssel = pOdd ? rB : Y;        /* sigmoid(o) on both lanes */    \
    const float ssel2 = ssel + ssel;         /* off-chain, under tanh lat */   \
    const float prod = sA * X;               /* KGc*si*tg on both lanes */     \
    const float cnp  = fmaf(fsel, cp, prod); /* KGc-scaled cell */             \
    const float rT   = frcp(1.0f + fexp2(cnp));                                \
    const float hn   = fmaf(ssel2, rT, -ssel); /* = ssel*(2*rT-1) */           \
    float hpost, cpost;                                                        \
    if (MASKF_) {                                                              \
        const bool act = (u_ >= 3 * L);      /* skew-3 pipeline-fill gate */   \
        cpost = act ? cnp : cp;                                                \
        hpost = act ? hn : Hx;                                                 \
    } else { cpost = cnp; hpost = hn; }                                        \
    cp = cpost;                                                                \
    su[u_] = gHi;                            /* head value on L=6 lanes */     \
    const float H2xN = swz4(hpost);          /* covered by next E-block */     \
    const float hpub = isFeeder ? (NXV_) : hpost;                              \
    const float hupNew = bpermf(addrA, hpub);                                  \
    Hx = hpost; H2x = H2xN;                                                    \
    hupE = hupM; hupM = hupNew; U2s = U2sN;                                    \
    E1c = E1n; E2c = E2n;                                                      \
} while (0)

// PREFM_: 0=no prefetch, 1=stream next 16 t's, 2=clamped (replicate t=2047)
#define RUN_CHUNK(cc_, cur_, nxt_, MASKF_, PREFM_, GUARDF_, NSTEPS_) do {      \
    if ((PREFM_) == 1) {                                                       \
        _Pragma("unroll")                                                      \
        for (int uu = 0; uu < CH; ++uu) { nxt_[uu] = x[wi]; wi += 4096; }      \
    } else if ((PREFM_) == 2) {                                                \
        const float xl = x[2047u * 4096u + xcol];                              \
        _Pragma("unroll")                                                      \
        for (int uu = 0; uu < CH; ++uu) nxt_[uu] = xl;                         \
    }                                                                          \
    _Pragma("unroll")                                                          \
    for (int uu = 0; uu < (NSTEPS_); ++uu) {                                   \
        if (uu < CH - 3) STEP(uu, cur_[uu + 3], MASKF_);                       \
        else             STEP(uu, nxt_[uu + 3 - CH], MASKF_);                  \
    }                                                                          \
    if (isOut) {                                                               \
        const int base = (cc_) * CH - 18;    /* head lags input by 18 steps */ \
        _Pragma("unroll")                                                      \
        for (int uu = 0; uu < (NSTEPS_); ++uu) {                               \
            const int t = base + uu;                                           \
            if (!(GUARDF_) || ((t >= 0) && (t < S_LEN)))                       \
                out[(size_t)t * BATCH + b] = su[uu];                           \
        }                                                                      \
    }                                                                          \
} while (0)

    // chunk 0: masked fill + guard; chunk 1: guard only (base = -2)
    RUN_CHUNK(0, bufP, bufQ, 1, 1, 1, CH);
    RUN_CHUNK(1, bufQ, bufP, 0, 1, 1, CH);
    // bulk: chunks 2..125, maskless, guardless, ping-pong buffers
#pragma unroll 1
    for (int cc = 2; cc < 126; cc += 2) {
        RUN_CHUNK(cc,     bufP, bufQ, 0, 1, 0, CH);
        RUN_CHUNK(cc + 1, bufQ, bufP, 0, 1, 0, CH);
    }
    // chunk 126: prefetch last real tile (t=2032..2047)
    RUN_CHUNK(126, bufP, bufQ, 0, 1, 0, CH);
    // chunks 127-128: clamped prefetch (t=2047 replicated)
    RUN_CHUNK(127, bufQ, bufP, 0, 2, 0, CH);
    RUN_CHUNK(128, bufP, bufQ, 0, 2, 0, CH);
    // chunk 129: 2 drain steps emit head values for t=2046..2047
    RUN_CHUNK(129, bufQ, bufP, 0, 0, 0, 2);
#undef RUN_CHUNK
#undef STEP
}

extern "C" void kernel_launch(void* const* d_in, const int* in_sizes, int n_in,
                              void* d_out, int out_size, void* d_ws, size_t ws_size,
                              hipStream_t stream) {
    const float* x     = (const float*)d_in[0];
    const float* w_ih  = (const float*)d_in[1];
    const float* w_hh  = (const float*)d_in[2];
    const float* b_ih  = (const float*)d_in[3];
    const float* b_hh  = (const float*)d_in[4];
    const float* reg_w = (const float*)d_in[5];
    const float* reg_b = (const float*)d_in[6];
    float* out = (float*)d_out;

    // 1024 single-wave blocks, one batch element each: 1 wave per SIMD.
    dim3 grid(BATCH);
    dim3 block(64);
    hipLaunchKernelGGL(lstm_wavepipe, grid, block, 0, stream, x, w_ih, w_hh,
                       b_ih, b_hh, reg_w, reg_b, out);
}

// Round 10
// 324.755 us; speedup vs baseline: 1.0020x; 1.0020x over previous
//
#include <hip/hip_runtime.h>

#define S_LEN  2048
#define BATCH  1024
#define NL     6
#define CH     16      // timesteps per chunk (x-prefetch granularity)

typedef float f32x2 __attribute__((ext_vector_type(2)));

__device__ __forceinline__ float fexp2(float x) { return __builtin_amdgcn_exp2f(x); }
__device__ __forceinline__ float frcp(float x)  { return __builtin_amdgcn_rcpf(x); }

// quad_perm DPP: 0xB1 = lane^1 (pair partner), 0x4E = lane^2 (unit^1)
template <int CTRL>
__device__ __forceinline__ float dppf(float v) {
    return __int_as_float(__builtin_amdgcn_update_dpp(
        0, __float_as_int(v), CTRL, 0xF, 0xF, true));
}
__device__ __forceinline__ float bpermf(int addr, float v) {
    return __int_as_float(__builtin_amdgcn_ds_bpermute(addr, __float_as_int(v)));
}
// lane^4 exchange (unit^2) via ds_swizzle BitMode: xor=4, and=0x1F -> 0x101F
__device__ __forceinline__ float swz4(float v) {
    return __int_as_float(__builtin_amdgcn_ds_swizzle(__float_as_int(v), 0x101F));
}
// packed fp32 fma: d.lo = a.lo*b.lo + c.lo ; d.hi = a.hi*b.hi + c.hi
__device__ __forceinline__ f32x2 pkfma(f32x2 a, f32x2 b, f32x2 c) {
    f32x2 d;
    asm("v_pk_fma_f32 %0, %1, %2, %3" : "=v"(d) : "v"(a), "v"(b), "v"(c));
    return d;
}
// packed cross-add: d.lo = a.lo + b.hi ; d.hi = a.hi + b.lo
__device__ __forceinline__ f32x2 pkadd_xswap(f32x2 a, f32x2 b) {
    f32x2 d;
    asm("v_pk_add_f32 %0, %1, %2 op_sel:[0,1] op_sel_hi:[1,0]"
        : "=v"(d) : "v"(a), "v"(b));
    return d;
}

// ONE wave = ONE batch element; 1024 waves fill all 1024 SIMDs.
// lane = L*8 + u*2 + p: L 0..5 layers, L=6 head, L=7 feeders; u = unit,
// p = gate-pair (p=0 -> {i,f}, p=1 -> {g,o}).
//
// SKEW-3 pipeline (layer L at step n computes t = n - 3L), R9 structure.
// R10 micro-cuts: gate cross-adds fused into one v_pk_add_f32 (op_sel);
// the two gate 1+e adds packed; hup^2 delivered by a SECOND bpermute at
// publish time (addrB = addrA ^ 16 -> same values as swz4-after-landing),
// giving both hup streams 2 full steps of slack and deleting the mid-step
// swz4 staging. Cell state KGc-scaled; both parities compute valid cn/hn;
// head rides in the gHi chain of the L=6 lanes.
__global__ __launch_bounds__(64, 1) void lstm_wavepipe(
    const float* __restrict__ x, const float* __restrict__ w_ih,
    const float* __restrict__ w_hh, const float* __restrict__ b_ih,
    const float* __restrict__ b_hh, const float* __restrict__ reg_w,
    const float* __restrict__ reg_b, float* __restrict__ out) {
    const int lane = threadIdx.x;
    const int L    = lane >> 3;
    const int q    = lane & 7;
    const int u    = q >> 1;
    const bool pOdd = (lane & 1);
    const int b    = blockIdx.x;
    const bool isFeeder = (L == 7);
    const bool isOut    = (lane == 48);      // head lane u=0,p=0

    const float KGc = -2.885390082f;         // -2*log2(e)  (tanh scale)
    const float KIc = -1.442695041f;         // -log2(e)    (sigmoid scale)

    // ---- weight preload (R8/R9 layout) ----
    // F1.x: gateLo h-terms {u,u^2}; F1.y: gateHi h-terms {u^1,u^3}
    // F2.x: gateHi h-terms {u,u^2}; F2.y: gateLo h-terms {u^1,u^3}
    // E1/E2 same with w_ih (hup); biases seed E1 via PB.
    f32x2 A1h[2], A2h[2], B1h[2], B2h[2], PB;
    if (L < NL) {
        const int gLoI = pOdd ? 2 : 0;       // i or g
        const int gHiI = pOdd ? 3 : 1;       // f or o
        const float klo = pOdd ? KGc : KIc;
        const float khi = KIc;
        const int rowLo = L * 16 + gLoI * 4 + u;
        const int rowHi = L * 16 + gHiI * 4 + u;
#pragma unroll
        for (int k = 0; k < 2; ++k) {        // k=0: {u,u^1}; k=1: {u^2,u^3}
            const int c0 = u ^ (2 * k);
            const int c1 = u ^ (2 * k + 1);
            f32x2 a1, a2, b1, b2;
            a1.x = w_hh[rowLo * 4 + c0] * klo; a1.y = w_hh[rowHi * 4 + c1] * khi;
            a2.x = w_hh[rowHi * 4 + c0] * khi; a2.y = w_hh[rowLo * 4 + c1] * klo;
            b1.x = w_ih[rowLo * 4 + c0] * klo; b1.y = w_ih[rowHi * 4 + c1] * khi;
            b2.x = w_ih[rowHi * 4 + c0] * khi; b2.y = w_ih[rowLo * 4 + c1] * klo;
            A1h[k] = a1; A2h[k] = a2; B1h[k] = b1; B2h[k] = b2;
        }
        PB.x = (b_ih[rowLo] + b_hh[rowLo]) * klo;
        PB.y = (b_ih[rowHi] + b_hh[rowHi]) * khi;
    } else if (L == 6) {                     // head: dot(reg_w, hup) in gHi
#pragma unroll
        for (int k = 0; k < 2; ++k) {
            f32x2 z; z.x = 0.0f; z.y = 0.0f;
            A1h[k] = z; A2h[k] = z;
            f32x2 b1; b1.x = 0.0f; b1.y = reg_w[u ^ (2 * k + 1)];
            f32x2 b2; b2.x = reg_w[u ^ (2 * k)]; b2.y = 0.0f;
            B1h[k] = b1; B2h[k] = b2;
        }
        PB.x = 0.0f; PB.y = reg_b[0];
    } else {                                 // feeders: all zero
#pragma unroll
        for (int k = 0; k < 2; ++k) {
            f32x2 z; z.x = 0.0f; z.y = 0.0f;
            A1h[k] = z; A2h[k] = z; B1h[k] = z; B2h[k] = z;
        }
        PB.x = 0.0f; PB.y = 0.0f;
    }
    // sA = fma(aLo, rA, bLo): p0 -> KGc*sigmoid(i), p1 -> tanh(g)
    const float aLo = pOdd ? 2.0f : KGc;
    const float bLo = pOdd ? -1.0f : 0.0f;
    f32x2 Z2;   Z2.x = 0.0f;   Z2.y = 0.0f;
    f32x2 ONE2; ONE2.x = 1.0f; ONE2.y = 1.0f;

    const int src   = (lane >= 8) ? (lane - 8) : (lane + 56);
    const int addrA = src << 2;              // layer above, unit u
    const int addrB = (src ^ 4) << 2;        // layer above, unit u^2

    float cp = 0.0f;                         // KGc-scaled cell state
    float Hx = 0.0f, H2x = 0.0f;             // h, h[u^2] (swz-staged)
    float bufP[CH], bufQ[CH], su[CH];
    const uint32_t xcol = (uint32_t)(b * 4 + u);
    uint32_t wi = xcol;
#pragma unroll
    for (int uu = 0; uu < CH; ++uu) { bufP[uu] = x[wi]; wi += 4096; }  // t=0..15

    // prologue (skew-3): feeders publish x[n+3] at step n; seed with
    // x[0] (E for step 0), x[1] (hupE/hup2E), x[2] (hupM/hup2M).
    const float pub0 = isFeeder ? bufP[0] : 0.0f;
    const float pub1 = isFeeder ? bufP[1] : 0.0f;
    const float pub2 = isFeeder ? bufP[2] : 0.0f;
    f32x2 E1c, E2c;
    {
        const float h0  = bpermf(addrA, pub0);
        const float h0b = bpermf(addrB, pub0);
        f32x2 U0; U0.x = h0;  U0.y = dppf<0x4E>(h0);
        f32x2 U2; U2.x = h0b; U2.y = dppf<0x4E>(h0b);
        E1c = pkfma(B1h[1], U2, pkfma(B1h[0], U0, PB));
        E2c = pkfma(B2h[1], U2, pkfma(B2h[0], U0, Z2));
    }
    float hupE  = bpermf(addrA, pub1);       // consumed by E-block at step 0
    float hup2E = bpermf(addrB, pub1);
    float hupM  = bpermf(addrA, pub2);       // becomes hupE at step 1
    float hup2M = bpermf(addrB, pub2);

// one pipeline step; NXV_ = x value the feeders publish (consumed at n+3)
#define STEP(u_, NXV_, MASKF_) do {                                            \
    /* E-block for step n+1 (hup streams landed >=1 step ago) */               \
    f32x2 Un, U2n;                                                             \
    Un.x  = hupE;   Un.y  = dppf<0x4E>(hupE);                                  \
    U2n.x = hup2E;  U2n.y = dppf<0x4E>(hup2E);                                 \
    f32x2 E1n = pkfma(B1h[0], Un, PB);                                         \
    f32x2 E2n = pkfma(B2h[0], Un, Z2);                                         \
    E1n = pkfma(B1h[1], U2n, E1n);                                             \
    E2n = pkfma(B2h[1], U2n, E2n);                                             \
    /* F-chain: own-h hop first, swz-dependent H2 hop last */                  \
    f32x2 Hh, H2h;                                                             \
    Hh.x = Hx;   Hh.y = dppf<0x4E>(Hx);                                        \
    H2h.x = H2x; H2h.y = dppf<0x4E>(H2x);                                      \
    f32x2 F1 = pkfma(A1h[0], Hh, E1c);                                         \
    f32x2 F2 = pkfma(A2h[0], Hh, E2c);                                         \
    F1 = pkfma(A1h[1], H2h, F1);                                               \
    F2 = pkfma(A2h[1], H2h, F2);                                               \
    const f32x2 G = pkadd_xswap(F1, F2);     /* {gLo, gHi} in one pk_add */    \
    /* activations */                                                          \
    f32x2 EB; EB.x = fexp2(G.x); EB.y = fexp2(G.y);                            \
    const f32x2 PP = EB + ONE2;              /* packed 1+e */                   \
    const float rA = frcp(PP.x);                                               \
    const float rB = frcp(PP.y);                                               \
    const float sA = fmaf(aLo, rA, bLo);     /* p0: KGc*si ; p1: tanh(g) */    \
    const float X  = dppf<0xB1>(sA);                                           \
    const float Y  = dppf<0xB1>(rB);                                           \
    const float fsel = pOdd ? Y : rB;        /* sigmoid(f) on both lanes */    \
    const float ssel = pOdd ? rB : Y;        /* sigmoid(o) on both lanes */    \
    const float ssel2 = ssel + ssel;         /* off-chain, under tanh lat */   \
    const float prod = sA * X;               /* KGc*si*tg on both lanes */     \
    const float cnp  = fmaf(fsel, cp, prod); /* KGc-scaled cell */             \
    const float rT   = frcp(1.0f + fexp2(cnp));                                \
    const float hn   = fmaf(ssel2, rT, -ssel); /* = ssel*(2*rT-1) */           \
    float hpost, cpost;                                                        \
    if (MASKF_) {                                                              \
        const bool act = (u_ >= 3 * L);      /* skew-3 pipeline-fill gate */   \
        cpost = act ? cnp : cp;                                                \
        hpost = act ? hn : Hx;                                                 \
    } else { cpost = cnp; hpost = hn; }                                        \
    cp = cpost;                                                                \
    su[u_] = G.y;                            /* head value on L=6 lanes */     \
    const float H2xN = swz4(hpost);          /* own-layer u^2, 1-step slack */ \
    const float hpub = isFeeder ? (NXV_) : hpost;                              \
    const float hupNew  = bpermf(addrA, hpub);                                 \
    const float hup2New = bpermf(addrB, hpub);                                 \
    Hx = hpost; H2x = H2xN;                                                    \
    hupE = hupM;   hupM = hupNew;                                              \
    hup2E = hup2M; hup2M = hup2New;                                            \
    E1c = E1n; E2c = E2n;                                                      \
} while (0)

// PREFM_: 0=no prefetch, 1=stream next 16 t's, 2=clamped (replicate t=2047)
#define RUN_CHUNK(cc_, cur_, nxt_, MASKF_, PREFM_, GUARDF_, NSTEPS_) do {      \
    if ((PREFM_) == 1) {                                                       \
        _Pragma("unroll")                                                      \
        for (int uu = 0; uu < CH; ++uu) { nxt_[uu] = x[wi]; wi += 4096; }      \
    } else if ((PREFM_) == 2) {                                                \
        const float xl = x[2047u * 4096u + xcol];                              \
        _Pragma("unroll")                                                      \
        for (int uu = 0; uu < CH; ++uu) nxt_[uu] = xl;                         \
    }                                                                          \
    _Pragma("unroll")                                                          \
    for (int uu = 0; uu < (NSTEPS_); ++uu) {                                   \
        if (uu < CH - 3) STEP(uu, cur_[uu + 3], MASKF_);                       \
        else             STEP(uu, nxt_[uu + 3 - CH], MASKF_);                  \
    }                                                                          \
    if (isOut) {                                                               \
        const int base = (cc_) * CH - 18;    /* head lags input by 18 steps */ \
        _Pragma("unroll")                                                      \
        for (int uu = 0; uu < (NSTEPS_); ++uu) {                               \
            const int t = base + uu;                                           \
            if (!(GUARDF_) || ((t >= 0) && (t < S_LEN)))                       \
                out[(size_t)t * BATCH + b] = su[uu];                           \
        }                                                                      \
    }                                                                          \
} while (0)

    // chunk 0: masked fill + guard; chunk 1: guard only (base = -2)
    RUN_CHUNK(0, bufP, bufQ, 1, 1, 1, CH);
    RUN_CHUNK(1, bufQ, bufP, 0, 1, 1, CH);
    // bulk: chunks 2..125, maskless, guardless, ping-pong buffers
#pragma unroll 1
    for (int cc = 2; cc < 126; cc += 2) {
        RUN_CHUNK(cc,     bufP, bufQ, 0, 1, 0, CH);
        RUN_CHUNK(cc + 1, bufQ, bufP, 0, 1, 0, CH);
    }
    // chunk 126: prefetch last real tile (t=2032..2047)
    RUN_CHUNK(126, bufP, bufQ, 0, 1, 0, CH);
    // chunks 127-128: clamped prefetch (t=2047 replicated)
    RUN_CHUNK(127, bufQ, bufP, 0, 2, 0, CH);
    RUN_CHUNK(128, bufP, bufQ, 0, 2, 0, CH);
    // chunk 129: 2 drain steps emit head values for t=2046..2047
    RUN_CHUNK(129, bufQ, bufP, 0, 0, 0, 2);
#undef RUN_CHUNK
#undef STEP
}

extern "C" void kernel_launch(void* const* d_in, const int* in_sizes, int n_in,
                              void* d_out, int out_size, void* d_ws, size_t ws_size,
                              hipStream_t stream) {
    const float* x     = (const float*)d_in[0];
    const float* w_ih  = (const float*)d_in[1];
    const float* w_hh  = (const float*)d_in[2];
    const float* b_ih  = (const float*)d_in[3];
    const float* b_hh  = (const float*)d_in[4];
    const float* reg_w = (const float*)d_in[5];
    const float* reg_b = (const float*)d_in[6];
    float* out = (float*)d_out;

    // 1024 single-wave blocks, one batch element each: 1 wave per SIMD.
    dim3 grid(BATCH);
    dim3 block(64);
    hipLaunchKernelGGL(lstm_wavepipe, grid, block, 0, stream, x, w_ih, w_hh,
                       b_ih, b_hh, reg_w, reg_b, out);
}